// Round 15
// baseline (74.314 us; speedup 1.0000x reference)
//
#include <hip/hip_runtime.h>

#define T_LEN 32768
#define TT 64
#define SWZ(row) ((((row) >> 1) & 7) << 4)

// LDS layout (bytes): xs 80*128, csA 64*128, csB 64*32
#define XS_OFF   0
#define CSA_OFF  10240
#define CSB_OFF  18432
#define LDS_SZ   20480

typedef unsigned short ushort;
typedef unsigned int uint;
typedef __attribute__((ext_vector_type(8))) short short8;   // 8 bf16
typedef __attribute__((ext_vector_type(4))) float f32x4;
typedef __attribute__((ext_vector_type(2))) uint uint2v;
typedef __attribute__((ext_vector_type(4))) uint uint4v;

// Fragment-packed bf16 weights (one linear blob, L2-resident, read by all blocks).
// ushort layout: [0,32768) A1 full k-steps; [32768,34816) A8 half-frags; [34816,38912) A2.
// A-frag and B-frag lane layouts coincide byte-for-byte (lane&15 -> 16-dim,
// lane>>4 -> k-octet), so the same bytes serve W (A-op) or W^T (B-op).
__device__ __align__(16) ushort g_packAll[38912];

static __device__ __forceinline__ ushort f2bf(float f) {    // RNE f32->bf16 (pack kernel only)
    uint u = __float_as_uint(f);
    u += 0x7fffu + ((u >> 16) & 1u);
    return (ushort)(u >> 16);
}
// 1-inst RNE pack of two f32 -> 2xbf16 (lo in bits[15:0], hi in bits[31:16])
static __device__ __forceinline__ uint cvtpk(float lo, float hi) {
    uint r;
    asm("v_cvt_pk_bf16_f32 %0, %1, %2" : "=v"(r) : "v"(lo), "v"(hi));
    return r;
}

__global__ void pack_weights(const float* __restrict__ wconv,
                             const float* __restrict__ wcond,
                             const float* __restrict__ wout) {
    int idx = blockIdx.x * 256 + threadIdx.x;
    if (idx >= 38912) return;
    float v;
    if (idx < 32768) {                   // A1 full k-steps s=0..7 (conv 6 + cond 2)
        int j = idx & 7, lane = (idx >> 3) & 63, f = idx >> 9;  // f = s*8+g
        int s = f >> 3, g = f & 7;
        int row = (g & 3) * 16 + (lane & 15) + ((g & 4) ? 64 : 0);
        int k = s * 32 + (lane >> 4) * 8 + j;
        if (k < 192) v = wconv[row * 192 + (k & 63) * 3 + (k >> 6)];  // tap-major k
        else         v = wcond[row * 80 + (k - 192)];
    } else if (idx < 34816) {            // s=8 half-frags: k = cc 64..79 (l4<2 lanes)
        int e = idx - 32768;
        int j = e & 7, lane32 = (e >> 3) & 31, g = e >> 8;
        int row = (g & 3) * 16 + (lane32 & 15) + ((g & 4) ? 64 : 0);
        v = wcond[row * 80 + 64 + (lane32 >> 4) * 8 + j];
    } else {                             // A2: wout, f2 = s2*4 + m
        int e = idx - 34816;
        int j = e & 7, lane = (e >> 3) & 63, f2 = e >> 9;
        int row = (f2 & 3) * 16 + (lane & 15);
        v = wout[row * 64 + (f2 >> 2) * 32 + (lane >> 4) * 8 + j];
    }
    g_packAll[idx] = f2bf(v);
}

// 4096 blocks x 256 threads (4 waves), one 64-t tile each.
// R15: BOTH phases swapped (D rows = t). Wave wv owns channels wv*16..+16
// (and +64 for the gate half) over all 64 t. Each lane ends with 4 consecutive
// t of one channel -> ALL global stores are per-lane f32x4 NT (skip 16->4,
// out already 4). z -> LDS transpose via 16 ds_write_b16 (conflict-free).
__global__ __launch_bounds__(256, 4) void wavenet_mfma(
    const float* __restrict__ x, const float* __restrict__ cond,
    const float* __restrict__ bconv, const float* __restrict__ bout,
    float* __restrict__ out, float* __restrict__ skip)
{
    __shared__ __align__(16) char lds[LDS_SZ];
    const int tid = threadIdx.x;
    // XCD-aware swizzle: 512 consecutive t-tiles per XCD (bijective, 4096 % 8 == 0)
    const int bid = ((blockIdx.x & 7) << 9) | (blockIdx.x >> 3);
    const int b   = bid >> 9;
    const int t0  = (bid & 511) * TT;

    // ---- staging items: 0..159 x(oct,tq), 160..287 csA, 288..319 csB ----
    auto item_load = [&](int i, f32x4* v) {
        const float* p;
        bool ok = true;
        if (i < 160) {
            int oct = i & 7, tq = i >> 3;
            int g0 = t0 - 16 + tq * 4;
            ok = (g0 >= 0);
            p = x + (size_t)(b * 64 + oct * 8) * T_LEN + g0;
        } else if (i < 288) {
            int e = i - 160; int oct = e & 7, tq = e >> 3;
            p = cond + (size_t)(b * 80 + oct * 8) * T_LEN + t0 + tq * 4;
        } else {
            int e = i - 288; int octl = e & 1, tq = e >> 1;
            p = cond + (size_t)(b * 80 + 64 + octl * 8) * T_LEN + t0 + tq * 4;
        }
        if (ok) {
            #pragma unroll
            for (int j = 0; j < 8; ++j) v[j] = *(const f32x4*)(p + (size_t)j * T_LEN);
        } else {
            #pragma unroll
            for (int j = 0; j < 8; ++j) v[j] = (f32x4){0.f, 0.f, 0.f, 0.f};
        }
    };
    auto item_write = [&](int i, const f32x4* v) {
        char* basep; int tl, chunk; bool isB = false;
        if (i < 160)      { basep = lds + XS_OFF;  tl = (i >> 3) * 4;               chunk = (i & 7) * 16; }
        else if (i < 288) { int e = i - 160; basep = lds + CSA_OFF; tl = (e >> 3) * 4; chunk = (e & 7) * 16; }
        else              { int e = i - 288; basep = lds + CSB_OFF; tl = (e >> 1) * 4; chunk = (e & 1) * 16; isB = true; }
        #pragma unroll
        for (int r = 0; r < 4; ++r) {
            uint4v pk;
            #pragma unroll
            for (int q = 0; q < 4; ++q)
                pk[q] = cvtpk(v[2 * q][r], v[2 * q + 1][r]);   // ch 2q lo, 2q+1 hi
            int row = tl + r;
            int byte = isB ? row * 32 + (chunk ^ (((row >> 2) & 1) << 4))
                           : row * 128 + (chunk ^ SWZ(row));
            *(uint4v*)(basep + byte) = pk;
        }
    };

    // coverage: items [0,320), stride-256 loop
    for (int i = tid; i < 320; i += 256) {
        f32x4 va[8];
        item_load(i, va);
        item_write(i, va);
    }
    __syncthreads();

    const int lane = tid & 63, wv = tid >> 6;
    const int l4 = lane >> 4, l15 = lane & 15;
    const short8* pW = (const short8*)g_packAll;  // A1 at frag 0, A8 at 4096, A2 at 4352
    const short8 zero8 = (short8){0, 0, 0, 0, 0, 0, 0, 0};

    // ---- phase A (swapped): y^T[t][ch] = data^T * W^T + bconv ----
    // A-op = data^T frag from LDS (old B-read bytes, indexed by tf);
    // B-op = weight frag (same pW bytes/indices as the old A-op).
    const int ch = wv * 16 + l15;          // this lane's channel (tanh half)
    f32x4 accA[4], accG[4];
    {
        float ba_s = bconv[ch];
        float bg_s = bconv[64 + ch];
        #pragma unroll
        for (int tf = 0; tf < 4; ++tf) {
            accA[tf] = (f32x4){ba_s, ba_s, ba_s, ba_s};
            accG[tf] = (f32x4){bg_s, bg_s, bg_s, bg_s};
        }
    }

    short8 Wa = pW[(0 * 8 + wv) * 64 + lane];
    short8 Wg = pW[(0 * 8 + 4 + wv) * 64 + lane];
    #pragma unroll
    for (int s = 0; s < 9; ++s) {
        short8 Wan = zero8, Wgn = zero8;
        if (s < 7) {                     // prefetch next full k-step
            Wan = pW[((s + 1) * 8 + wv) * 64 + lane];
            Wgn = pW[((s + 1) * 8 + 4 + wv) * 64 + lane];
        } else if (s == 7) {             // prefetch s=8 half-frag (lanes l4<2 only;
            if (l4 < 2) {                //  l4>=2 zero -> k 16..31 contribute 0)
                Wan = pW[4096 + wv * 32 + lane];
                Wgn = pW[4096 + (4 + wv) * 32 + lane];
            }
        }
        #pragma unroll
        for (int tf = 0; tf < 4; ++tf) {
            int trow = tf * 16 + l15;
            short8 Ad;
            if (s < 6) {            // conv tap s>>1, c-half s&1; tap shifts t by 8*tap
                int tl = trow + (s >> 1) * 8;
                Ad = *(const short8*)(lds + XS_OFF + tl * 128 + (((s & 1) * 64 + l4 * 16) ^ SWZ(tl)));
            } else if (s < 8) {     // cond cc (s-6)*32..+32
                Ad = *(const short8*)(lds + CSA_OFF + trow * 128 + (((s - 6) * 64 + l4 * 16) ^ SWZ(trow)));
            } else {                // cond cc 64..79 (half-K)
                Ad = *(const short8*)(lds + CSB_OFF + trow * 32 + (((l4 & 1) * 16) ^ (((trow >> 2) & 1) << 4)));
            }
            accA[tf] = __builtin_amdgcn_mfma_f32_16x16x32_bf16(Ad, Wa, accA[tf], 0, 0, 0);
            accG[tf] = __builtin_amdgcn_mfma_f32_16x16x32_bf16(Ad, Wg, accG[tf], 0, 0, 0);
        }
        Wa = Wan; Wg = Wgn;
    }
    __syncthreads();   // xs/csA/csB reads done -> zs may overlay

    // ---- gate (register-only) + f32x4 NT skip store + z -> LDS (b16 transpose) ----
    char* zs = lds + XS_OFF;    // [64 t][64 r] bf16, 128B rows, SWZ on t
    {
        const int cb2 = ch * 2;
        #pragma unroll
        for (int tf = 0; tf < 4; ++tf) {
            f32x4 z;
            #pragma unroll
            for (int j = 0; j < 4; ++j) {
                float a = accA[tf][j], g = accG[tf][j];
                float th = 1.f - 2.f * __builtin_amdgcn_rcpf(__expf(2.f * a) + 1.f);
                float sg = __builtin_amdgcn_rcpf(1.f + __expf(-g));
                z[j] = th * sg;
            }
            int tb = t0 + tf * 16 + l4 * 4;
            __builtin_nontemporal_store(z, (f32x4*)&skip[(size_t)(b * 64 + ch) * T_LEN + tb]);
            uint u01 = cvtpk(z[0], z[1]);
            uint u23 = cvtpk(z[2], z[3]);
            int tl = tf * 16 + l4 * 4;
            *(ushort*)(zs + (tl + 0) * 128 + (cb2 ^ SWZ(tl + 0))) = (ushort)u01;
            *(ushort*)(zs + (tl + 1) * 128 + (cb2 ^ SWZ(tl + 1))) = (ushort)(u01 >> 16);
            *(ushort*)(zs + (tl + 2) * 128 + (cb2 ^ SWZ(tl + 2))) = (ushort)u23;
            *(ushort*)(zs + (tl + 3) * 128 + (cb2 ^ SWZ(tl + 3))) = (ushort)(u23 >> 16);
        }
    }
    __syncthreads();

    // ---- phase B (swapped, as R14): out^T[t][och] = z^T * Wout^T + bout ----
    const float bo_s = bout[wv * 16 + l15];
    f32x4 accO[4];
    #pragma unroll
    for (int tf = 0; tf < 4; ++tf) accO[tf] = (f32x4){bo_s, bo_s, bo_s, bo_s};

    short8 Bw = pW[4352 + (0 * 4 + wv) * 64 + lane];
    #pragma unroll
    for (int s2 = 0; s2 < 2; ++s2) {
        short8 Bwn = zero8;
        if (s2 == 0) Bwn = pW[4352 + (1 * 4 + wv) * 64 + lane];
        #pragma unroll
        for (int tf = 0; tf < 4; ++tf) {
            int colt = tf * 16 + l15;
            short8 Az = *(const short8*)(zs + colt * 128 + ((s2 * 64 + l4 * 16) ^ SWZ(colt)));
            accO[tf] = __builtin_amdgcn_mfma_f32_16x16x32_bf16(Az, Bw, accO[tf], 0, 0, 0);
        }
        Bw = Bwn;
    }
    #pragma unroll
    for (int tf = 0; tf < 4; ++tf) {
        size_t cho = (size_t)(b * 64 + wv * 16 + l15);
        int tg = t0 + tf * 16 + l4 * 4;
        __builtin_nontemporal_store(accO[tf], (f32x4*)&out[cho * T_LEN + tg]);
    }
}

extern "C" void kernel_launch(void* const* d_in, const int* in_sizes, int n_in,
                              void* d_out, int out_size, void* d_ws, size_t ws_size,
                              hipStream_t stream) {
    const float* x     = (const float*)d_in[0];
    const float* cond  = (const float*)d_in[1];
    const float* wconv = (const float*)d_in[2];
    const float* bconv = (const float*)d_in[3];
    const float* wout  = (const float*)d_in[4];
    const float* bout  = (const float*)d_in[5];
    const float* wcond = (const float*)d_in[6];

    float* out  = (float*)d_out;
    float* skip = out + (size_t)8 * 64 * T_LEN;   // outputs concatenated in return order

    pack_weights<<<dim3(152), 256, 0, stream>>>(wconv, wcond, wout);
    wavenet_mfma<<<dim3(8 * (T_LEN / TT)), 256, 0, stream>>>(x, cond, bconv, bout, out, skip);
}

// Round 16
// 68.797 us; speedup vs baseline: 1.0802x; 1.0802x over previous
//
#include <hip/hip_runtime.h>

#define T_LEN 32768
#define TT 64
#define SWZ(row) ((((row) >> 1) & 7) << 4)

// LDS layout (bytes): xs 80*128, csA 64*128, csB 64*32; then (after phase A)
// zs overlays xs (8KB) and st (16KB f32 store-staging) overlays csA/csB+tail.
#define XS_OFF   0
#define CSA_OFF  10240
#define CSB_OFF  18432
#define ST_OFF   8192
#define LDS_SZ   24576

typedef unsigned short ushort;
typedef unsigned int uint;
typedef __attribute__((ext_vector_type(8))) short short8;   // 8 bf16
typedef __attribute__((ext_vector_type(4))) float f32x4;
typedef __attribute__((ext_vector_type(2))) uint uint2v;
typedef __attribute__((ext_vector_type(4))) uint uint4v;

// Fragment-packed bf16 weights (one linear blob, L2-resident, read by all blocks).
// ushort layout: [0,32768) A1 full k-steps; [32768,34816) A8 half-frags; [34816,38912) A2.
// A-frag and B-frag lane layouts coincide byte-for-byte, so the same bytes
// serve W (A-op) or W^T (B-op).
__device__ __align__(16) ushort g_packAll[38912];

static __device__ __forceinline__ ushort f2bf(float f) {    // RNE f32->bf16 (pack kernel only)
    uint u = __float_as_uint(f);
    u += 0x7fffu + ((u >> 16) & 1u);
    return (ushort)(u >> 16);
}
// 1-inst RNE pack of two f32 -> 2xbf16 (lo in bits[15:0], hi in bits[31:16])
static __device__ __forceinline__ uint cvtpk(float lo, float hi) {
    uint r;
    asm("v_cvt_pk_bf16_f32 %0, %1, %2" : "=v"(r) : "v"(lo), "v"(hi));
    return r;
}

__global__ void pack_weights(const float* __restrict__ wconv,
                             const float* __restrict__ wcond,
                             const float* __restrict__ wout) {
    int idx = blockIdx.x * 256 + threadIdx.x;
    if (idx >= 38912) return;
    float v;
    if (idx < 32768) {                   // A1 full k-steps s=0..7 (conv 6 + cond 2)
        int j = idx & 7, lane = (idx >> 3) & 63, f = idx >> 9;  // f = s*8+g
        int s = f >> 3, g = f & 7;
        int row = (g & 3) * 16 + (lane & 15) + ((g & 4) ? 64 : 0);
        int k = s * 32 + (lane >> 4) * 8 + j;
        if (k < 192) v = wconv[row * 192 + (k & 63) * 3 + (k >> 6)];  // tap-major k
        else         v = wcond[row * 80 + (k - 192)];
    } else if (idx < 34816) {            // s=8 half-frags: k = cc 64..79 (l4<2 lanes)
        int e = idx - 32768;
        int j = e & 7, lane32 = (e >> 3) & 31, g = e >> 8;
        int row = (g & 3) * 16 + (lane32 & 15) + ((g & 4) ? 64 : 0);
        v = wcond[row * 80 + 64 + (lane32 >> 4) * 8 + j];
    } else {                             // A2: wout, f2 = s2*4 + m
        int e = idx - 34816;
        int j = e & 7, lane = (e >> 3) & 63, f2 = e >> 9;
        int row = (f2 & 3) * 16 + (lane & 15);
        v = wout[row * 64 + (f2 >> 2) * 32 + (lane >> 4) * 8 + j];
    }
    g_packAll[idx] = f2bf(v);
}

// 4096 blocks x 256 threads (4 waves), one 64-t tile each. Both phases swapped
// (D rows = t); wave wv owns channels wv*16..+16 (and +64 gate half).
// R16: out/skip go through a 16KB LDS f32 staging buffer with XOR-involution
// slot swizzle, then each wave NT-stores its own 16 channels as 256B-contiguous
// runs (4 ch x 16 lanes x f32x4 per instruction) -- widens DRAM write runs
// 64B -> 256B (full L2 lines). All staging is intra-wave: no new barriers.
__global__ __launch_bounds__(256, 4) void wavenet_mfma(
    const float* __restrict__ x, const float* __restrict__ cond,
    const float* __restrict__ bconv, const float* __restrict__ bout,
    float* __restrict__ out, float* __restrict__ skip)
{
    __shared__ __align__(16) char lds[LDS_SZ];
    const int tid = threadIdx.x;
    // XCD-aware swizzle: 512 consecutive t-tiles per XCD (bijective, 4096 % 8 == 0)
    const int bid = ((blockIdx.x & 7) << 9) | (blockIdx.x >> 3);
    const int b   = bid >> 9;
    const int t0  = (bid & 511) * TT;

    // ---- staging items: 0..159 x(oct,tq), 160..287 csA, 288..319 csB ----
    auto item_load = [&](int i, f32x4* v) {
        const float* p;
        bool ok = true;
        if (i < 160) {
            int oct = i & 7, tq = i >> 3;
            int g0 = t0 - 16 + tq * 4;
            ok = (g0 >= 0);
            p = x + (size_t)(b * 64 + oct * 8) * T_LEN + g0;
        } else if (i < 288) {
            int e = i - 160; int oct = e & 7, tq = e >> 3;
            p = cond + (size_t)(b * 80 + oct * 8) * T_LEN + t0 + tq * 4;
        } else {
            int e = i - 288; int octl = e & 1, tq = e >> 1;
            p = cond + (size_t)(b * 80 + 64 + octl * 8) * T_LEN + t0 + tq * 4;
        }
        if (ok) {
            #pragma unroll
            for (int j = 0; j < 8; ++j) v[j] = *(const f32x4*)(p + (size_t)j * T_LEN);
        } else {
            #pragma unroll
            for (int j = 0; j < 8; ++j) v[j] = (f32x4){0.f, 0.f, 0.f, 0.f};
        }
    };
    auto item_write = [&](int i, const f32x4* v) {
        char* basep; int tl, chunk; bool isB = false;
        if (i < 160)      { basep = lds + XS_OFF;  tl = (i >> 3) * 4;               chunk = (i & 7) * 16; }
        else if (i < 288) { int e = i - 160; basep = lds + CSA_OFF; tl = (e >> 3) * 4; chunk = (e & 7) * 16; }
        else              { int e = i - 288; basep = lds + CSB_OFF; tl = (e >> 1) * 4; chunk = (e & 1) * 16; isB = true; }
        #pragma unroll
        for (int r = 0; r < 4; ++r) {
            uint4v pk;
            #pragma unroll
            for (int q = 0; q < 4; ++q)
                pk[q] = cvtpk(v[2 * q][r], v[2 * q + 1][r]);   // ch 2q lo, 2q+1 hi
            int row = tl + r;
            int byte = isB ? row * 32 + (chunk ^ (((row >> 2) & 1) << 4))
                           : row * 128 + (chunk ^ SWZ(row));
            *(uint4v*)(basep + byte) = pk;
        }
    };

    // coverage: items [0,320), stride-256 loop
    for (int i = tid; i < 320; i += 256) {
        f32x4 va[8];
        item_load(i, va);
        item_write(i, va);
    }
    __syncthreads();

    const int lane = tid & 63, wv = tid >> 6;
    const int l4 = lane >> 4, l15 = lane & 15;
    const short8* pW = (const short8*)g_packAll;  // A1 at frag 0, A8 at 4096, A2 at 4352
    const short8 zero8 = (short8){0, 0, 0, 0, 0, 0, 0, 0};

    // ---- phase A (swapped): y^T[t][ch] = data^T * W^T + bconv ----
    const int ch = wv * 16 + l15;          // this lane's channel (tanh half)
    f32x4 accA[4], accG[4];
    {
        float ba_s = bconv[ch];
        float bg_s = bconv[64 + ch];
        #pragma unroll
        for (int tf = 0; tf < 4; ++tf) {
            accA[tf] = (f32x4){ba_s, ba_s, ba_s, ba_s};
            accG[tf] = (f32x4){bg_s, bg_s, bg_s, bg_s};
        }
    }

    short8 Wa = pW[(0 * 8 + wv) * 64 + lane];
    short8 Wg = pW[(0 * 8 + 4 + wv) * 64 + lane];
    #pragma unroll
    for (int s = 0; s < 9; ++s) {
        short8 Wan = zero8, Wgn = zero8;
        if (s < 7) {                     // prefetch next full k-step
            Wan = pW[((s + 1) * 8 + wv) * 64 + lane];
            Wgn = pW[((s + 1) * 8 + 4 + wv) * 64 + lane];
        } else if (s == 7) {             // prefetch s=8 half-frag (lanes l4<2 only)
            if (l4 < 2) {
                Wan = pW[4096 + wv * 32 + lane];
                Wgn = pW[4096 + (4 + wv) * 32 + lane];
            }
        }
        #pragma unroll
        for (int tf = 0; tf < 4; ++tf) {
            int trow = tf * 16 + l15;
            short8 Ad;
            if (s < 6) {            // conv tap s>>1, c-half s&1; tap shifts t by 8*tap
                int tl = trow + (s >> 1) * 8;
                Ad = *(const short8*)(lds + XS_OFF + tl * 128 + (((s & 1) * 64 + l4 * 16) ^ SWZ(tl)));
            } else if (s < 8) {     // cond cc (s-6)*32..+32
                Ad = *(const short8*)(lds + CSA_OFF + trow * 128 + (((s - 6) * 64 + l4 * 16) ^ SWZ(trow)));
            } else {                // cond cc 64..79 (half-K)
                Ad = *(const short8*)(lds + CSB_OFF + trow * 32 + (((l4 & 1) * 16) ^ (((trow >> 2) & 1) << 4)));
            }
            accA[tf] = __builtin_amdgcn_mfma_f32_16x16x32_bf16(Ad, Wa, accA[tf], 0, 0, 0);
            accG[tf] = __builtin_amdgcn_mfma_f32_16x16x32_bf16(Ad, Wg, accG[tf], 0, 0, 0);
        }
        Wa = Wan; Wg = Wgn;
    }
    __syncthreads();   // xs/csA/csB reads done -> zs/st may overlay

    // ---- gate (register-only): z -> st (f32, for skip) + zs (bf16, for B) ----
    char* zs = lds + XS_OFF;    // [64 t][64 ch] bf16, 128B rows, SWZ on t
    char* st = lds + ST_OFF;    // [64 ch][64 t] f32, 256B rows, slot ^= (ch&15)
    {
        const int cb2 = ch * 2;
        #pragma unroll
        for (int tf = 0; tf < 4; ++tf) {
            f32x4 z;
            #pragma unroll
            for (int j = 0; j < 4; ++j) {
                float a = accA[tf][j], g = accG[tf][j];
                float th = 1.f - 2.f * __builtin_amdgcn_rcpf(__expf(2.f * a) + 1.f);
                float sg = __builtin_amdgcn_rcpf(1.f + __expf(-g));
                z[j] = th * sg;
            }
            // f32 staging: (ch, tchunk = tf*4+l4) at slot tchunk^(ch&15)
            *(f32x4*)(st + ch * 256 + (((tf * 4 + l4) ^ l15) << 4)) = z;
            // bf16 transpose into zs for phase B
            uint u01 = cvtpk(z[0], z[1]);
            uint u23 = cvtpk(z[2], z[3]);
            int tl = tf * 16 + l4 * 4;
            *(ushort*)(zs + (tl + 0) * 128 + (cb2 ^ SWZ(tl + 0))) = (ushort)u01;
            *(ushort*)(zs + (tl + 1) * 128 + (cb2 ^ SWZ(tl + 1))) = (ushort)(u01 >> 16);
            *(ushort*)(zs + (tl + 2) * 128 + (cb2 ^ SWZ(tl + 2))) = (ushort)u23;
            *(ushort*)(zs + (tl + 3) * 128 + (cb2 ^ SWZ(tl + 3))) = (ushort)(u23 >> 16);
        }
    }
    __syncthreads();   // zs visible cross-wave (st is intra-wave only)

    // ---- coop skip store: 256B-contiguous runs (4 ch x 16 lanes x f32x4) ----
    #pragma unroll
    for (int i = 0; i < 4; ++i) {
        int c2 = wv * 16 + i * 4 + l4;     // this wave's own channels
        f32x4 v = *(const f32x4*)(st + c2 * 256 + ((l15 ^ (i * 4 + l4)) << 4));
        __builtin_nontemporal_store(v, (f32x4*)&skip[(size_t)(b * 64 + c2) * T_LEN + t0 + l15 * 4]);
    }

    // ---- phase B (swapped): out^T[t][och] = z^T * Wout^T + bout ----
    const float bo_s = bout[wv * 16 + l15];
    f32x4 accO[4];
    #pragma unroll
    for (int tf = 0; tf < 4; ++tf) accO[tf] = (f32x4){bo_s, bo_s, bo_s, bo_s};

    short8 Bw = pW[4352 + (0 * 4 + wv) * 64 + lane];
    #pragma unroll
    for (int s2 = 0; s2 < 2; ++s2) {
        short8 Bwn = zero8;
        if (s2 == 0) Bwn = pW[4352 + (1 * 4 + wv) * 64 + lane];
        #pragma unroll
        for (int tf = 0; tf < 4; ++tf) {
            int colt = tf * 16 + l15;
            short8 Az = *(const short8*)(zs + colt * 128 + ((s2 * 64 + l4 * 16) ^ SWZ(colt)));
            accO[tf] = __builtin_amdgcn_mfma_f32_16x16x32_bf16(Az, Bw, accO[tf], 0, 0, 0);
        }
        Bw = Bwn;
    }
    // staging (overwrites this wave's own region AFTER its skip reads: program order)
    #pragma unroll
    for (int tf = 0; tf < 4; ++tf)
        *(f32x4*)(st + ch * 256 + (((tf * 4 + l4) ^ l15) << 4)) = accO[tf];
    // ---- coop out store: 256B-contiguous runs ----
    #pragma unroll
    for (int i = 0; i < 4; ++i) {
        int c2 = wv * 16 + i * 4 + l4;
        f32x4 v = *(const f32x4*)(st + c2 * 256 + ((l15 ^ (i * 4 + l4)) << 4));
        __builtin_nontemporal_store(v, (f32x4*)&out[(size_t)(b * 64 + c2) * T_LEN + t0 + l15 * 4]);
    }
}

extern "C" void kernel_launch(void* const* d_in, const int* in_sizes, int n_in,
                              void* d_out, int out_size, void* d_ws, size_t ws_size,
                              hipStream_t stream) {
    const float* x     = (const float*)d_in[0];
    const float* cond  = (const float*)d_in[1];
    const float* wconv = (const float*)d_in[2];
    const float* bconv = (const float*)d_in[3];
    const float* wout  = (const float*)d_in[4];
    const float* bout  = (const float*)d_in[5];
    const float* wcond = (const float*)d_in[6];

    float* out  = (float*)d_out;
    float* skip = out + (size_t)8 * 64 * T_LEN;   // outputs concatenated in return order

    pack_weights<<<dim3(152), 256, 0, stream>>>(wconv, wcond, wout);
    wavenet_mfma<<<dim3(8 * (T_LEN / TT)), 256, 0, stream>>>(x, cond, bconv, bout, out, skip);
}

// Round 17
// 65.473 us; speedup vs baseline: 1.1350x; 1.0508x over previous
//
#include <hip/hip_runtime.h>

#define T_LEN 32768
#define TT 64
#define SWZ(row) ((((row) >> 1) & 7) << 4)

// LDS (20480 B -> 8 blocks/CU = 160 KiB exactly):
// phase 1: xs[80][128] @0, csA[64][128] @10240, csB[64][32] @18432
// phase 2: zs[64t][64ch] bf16 @0 (8K, overlays xs)
// phase 3 (after barrier 4): st[64ch][64t] f32 @0 (16K, overlays zs+csA-head)
#define XS_OFF   0
#define CSA_OFF  10240
#define CSB_OFF  18432
#define LDS_SZ   20480

typedef unsigned short ushort;
typedef unsigned int uint;
typedef __attribute__((ext_vector_type(8))) short short8;   // 8 bf16
typedef __attribute__((ext_vector_type(4))) float f32x4;
typedef __attribute__((ext_vector_type(4))) uint uint4v;

// Fragment-packed bf16 weights (one linear blob, L2-resident, read by all blocks).
// ushort layout: [0,32768) A1 full k-steps; [32768,34816) A8 half-frags; [34816,38912) A2.
// A-frag and B-frag lane layouts coincide byte-for-byte, so the same bytes
// serve W (A-op) or W^T (B-op).
__device__ __align__(16) ushort g_packAll[38912];

static __device__ __forceinline__ ushort f2bf(float f) {    // RNE f32->bf16 (pack kernel only)
    uint u = __float_as_uint(f);
    u += 0x7fffu + ((u >> 16) & 1u);
    return (ushort)(u >> 16);
}
// 1-inst RNE pack of two f32 -> 2xbf16
static __device__ __forceinline__ uint cvtpk(float lo, float hi) {
    uint r;
    asm("v_cvt_pk_bf16_f32 %0, %1, %2" : "=v"(r) : "v"(lo), "v"(hi));
    return r;
}

__global__ void pack_weights(const float* __restrict__ wconv,
                             const float* __restrict__ wcond,
                             const float* __restrict__ wout) {
    int idx = blockIdx.x * 256 + threadIdx.x;
    if (idx >= 38912) return;
    float v;
    if (idx < 32768) {                   // A1 full k-steps s=0..7 (conv 6 + cond 2)
        int j = idx & 7, lane = (idx >> 3) & 63, f = idx >> 9;  // f = s*8+g
        int s = f >> 3, g = f & 7;
        int row = (g & 3) * 16 + (lane & 15) + ((g & 4) ? 64 : 0);
        int k = s * 32 + (lane >> 4) * 8 + j;
        if (k < 192) v = wconv[row * 192 + (k & 63) * 3 + (k >> 6)];  // tap-major k
        else         v = wcond[row * 80 + (k - 192)];
    } else if (idx < 34816) {            // s=8 half-frags: k = cc 64..79 (l4<2 lanes)
        int e = idx - 32768;
        int j = e & 7, lane32 = (e >> 3) & 31, g = e >> 8;
        int row = (g & 3) * 16 + (lane32 & 15) + ((g & 4) ? 64 : 0);
        v = wcond[row * 80 + 64 + (lane32 >> 4) * 8 + j];
    } else {                             // A2: wout, f2 = s2*4 + m
        int e = idx - 34816;
        int j = e & 7, lane = (e >> 3) & 63, f2 = e >> 9;
        int row = (f2 & 3) * 16 + (lane & 15);
        v = wout[row * 64 + (f2 >> 2) * 32 + (lane >> 4) * 8 + j];
    }
    g_packAll[idx] = f2bf(v);
}

// 4096 blocks x 256 threads (4 waves), one 64-t tile each. Both phases swapped
// (D rows = t); wave wv owns channels wv*16..+16 (and +64 gate half).
// R17: LDS packed to 20480 (8 blocks/CU); read runs widened to 256-320 B;
// skip served from zs (bf16 z re-expanded, error budget holds); out staged
// through st overlaying zs after a new barrier. Coop 256B-run NT stores kept.
__global__ __launch_bounds__(256, 4) void wavenet_mfma(
    const float* __restrict__ x, const float* __restrict__ cond,
    const float* __restrict__ bconv, const float* __restrict__ bout,
    float* __restrict__ out, float* __restrict__ skip)
{
    __shared__ __align__(16) char lds[LDS_SZ];
    const int tid = threadIdx.x;
    // XCD-aware swizzle: 512 consecutive t-tiles per XCD (bijective, 4096 % 8 == 0)
    const int bid = ((blockIdx.x & 7) << 9) | (blockIdx.x >> 3);
    const int b   = bid >> 9;
    const int t0  = (bid & 511) * TT;

    // ---- staging items (remapped for long read runs):
    //   x:   i in [0,160)  : oct = i/20, tq = i%20  -> 320 B runs
    //   csA: e in [0,128)  : oct = e>>4, tq = e&15  -> 256 B runs
    //   csB: e in [0,32)   : octl= e>>4, tq = e&15  -> 256 B runs
    auto item_load = [&](int i, f32x4* v) {
        const float* p;
        bool ok = true;
        if (i < 160) {
            int oct = i / 20, tq = i - oct * 20;
            int g0 = t0 - 16 + tq * 4;
            ok = (g0 >= 0);
            p = x + (size_t)(b * 64 + oct * 8) * T_LEN + g0;
        } else if (i < 288) {
            int e = i - 160; int oct = e >> 4, tq = e & 15;
            p = cond + (size_t)(b * 80 + oct * 8) * T_LEN + t0 + tq * 4;
        } else {
            int e = i - 288; int octl = e >> 4, tq = e & 15;
            p = cond + (size_t)(b * 80 + 64 + octl * 8) * T_LEN + t0 + tq * 4;
        }
        if (ok) {
            #pragma unroll
            for (int j = 0; j < 8; ++j) v[j] = *(const f32x4*)(p + (size_t)j * T_LEN);
        } else {
            #pragma unroll
            for (int j = 0; j < 8; ++j) v[j] = (f32x4){0.f, 0.f, 0.f, 0.f};
        }
    };
    auto item_write = [&](int i, const f32x4* v) {
        char* basep; int tl, chunk; bool isB = false;
        if (i < 160)      { int oct = i / 20;  basep = lds + XS_OFF;  tl = (i - oct * 20) * 4; chunk = oct * 16; }
        else if (i < 288) { int e = i - 160;   basep = lds + CSA_OFF; tl = (e & 15) * 4;       chunk = (e >> 4) * 16; }
        else              { int e = i - 288;   basep = lds + CSB_OFF; tl = (e & 15) * 4;       chunk = (e >> 4) * 16; isB = true; }
        #pragma unroll
        for (int r = 0; r < 4; ++r) {
            uint4v pk;
            #pragma unroll
            for (int q = 0; q < 4; ++q)
                pk[q] = cvtpk(v[2 * q][r], v[2 * q + 1][r]);   // ch 2q lo, 2q+1 hi
            int row = tl + r;
            int byte = isB ? row * 32 + (chunk ^ (((row >> 2) & 1) << 4))
                           : row * 128 + (chunk ^ SWZ(row));
            *(uint4v*)(basep + byte) = pk;
        }
    };

    // coverage: items [0,320), stride-256 loop
    for (int i = tid; i < 320; i += 256) {
        f32x4 va[8];
        item_load(i, va);
        item_write(i, va);
    }
    __syncthreads();                      // (1) staged tile visible

    const int lane = tid & 63, wv = tid >> 6;
    const int l4 = lane >> 4, l15 = lane & 15;
    const short8* pW = (const short8*)g_packAll;  // A1 at frag 0, A8 at 4096, A2 at 4352
    const short8 zero8 = (short8){0, 0, 0, 0, 0, 0, 0, 0};

    // ---- phase A (swapped): y^T[t][ch] = data^T * W^T + bconv ----
    const int ch = wv * 16 + l15;          // this lane's channel (tanh half)
    f32x4 accA[4], accG[4];
    {
        float ba_s = bconv[ch];
        float bg_s = bconv[64 + ch];
        #pragma unroll
        for (int tf = 0; tf < 4; ++tf) {
            accA[tf] = (f32x4){ba_s, ba_s, ba_s, ba_s};
            accG[tf] = (f32x4){bg_s, bg_s, bg_s, bg_s};
        }
    }

    short8 Wa = pW[(0 * 8 + wv) * 64 + lane];
    short8 Wg = pW[(0 * 8 + 4 + wv) * 64 + lane];
    #pragma unroll
    for (int s = 0; s < 9; ++s) {
        short8 Wan = zero8, Wgn = zero8;
        if (s < 7) {                     // prefetch next full k-step
            Wan = pW[((s + 1) * 8 + wv) * 64 + lane];
            Wgn = pW[((s + 1) * 8 + 4 + wv) * 64 + lane];
        } else if (s == 7) {             // prefetch s=8 half-frag (lanes l4<2 only)
            if (l4 < 2) {
                Wan = pW[4096 + wv * 32 + lane];
                Wgn = pW[4096 + (4 + wv) * 32 + lane];
            }
        }
        #pragma unroll
        for (int tf = 0; tf < 4; ++tf) {
            int trow = tf * 16 + l15;
            short8 Ad;
            if (s < 6) {            // conv tap s>>1, c-half s&1; tap shifts t by 8*tap
                int tl = trow + (s >> 1) * 8;
                Ad = *(const short8*)(lds + XS_OFF + tl * 128 + (((s & 1) * 64 + l4 * 16) ^ SWZ(tl)));
            } else if (s < 8) {     // cond cc (s-6)*32..+32
                Ad = *(const short8*)(lds + CSA_OFF + trow * 128 + (((s - 6) * 64 + l4 * 16) ^ SWZ(trow)));
            } else {                // cond cc 64..79 (half-K)
                Ad = *(const short8*)(lds + CSB_OFF + trow * 32 + (((l4 & 1) * 16) ^ (((trow >> 2) & 1) << 4)));
            }
            accA[tf] = __builtin_amdgcn_mfma_f32_16x16x32_bf16(Ad, Wa, accA[tf], 0, 0, 0);
            accG[tf] = __builtin_amdgcn_mfma_f32_16x16x32_bf16(Ad, Wg, accG[tf], 0, 0, 0);
        }
        Wa = Wan; Wg = Wgn;
    }
    __syncthreads();                      // (2) xs/csA/csB reads done -> zs overlay ok

    // ---- gate (register-only): z -> zs (bf16) only ----
    char* zs = lds + XS_OFF;    // [64 t][64 ch] bf16, 128B rows, SWZ on t
    {
        const int cb2 = ch * 2;
        #pragma unroll
        for (int tf = 0; tf < 4; ++tf) {
            float z[4];
            #pragma unroll
            for (int j = 0; j < 4; ++j) {
                float a = accA[tf][j], g = accG[tf][j];
                float th = 1.f - 2.f * __builtin_amdgcn_rcpf(__expf(2.f * a) + 1.f);
                float sg = __builtin_amdgcn_rcpf(1.f + __expf(-g));
                z[j] = th * sg;
            }
            uint u01 = cvtpk(z[0], z[1]);
            uint u23 = cvtpk(z[2], z[3]);
            int tl = tf * 16 + l4 * 4;
            *(ushort*)(zs + (tl + 0) * 128 + (cb2 ^ SWZ(tl + 0))) = (ushort)u01;
            *(ushort*)(zs + (tl + 1) * 128 + (cb2 ^ SWZ(tl + 1))) = (ushort)(u01 >> 16);
            *(ushort*)(zs + (tl + 2) * 128 + (cb2 ^ SWZ(tl + 2))) = (ushort)u23;
            *(ushort*)(zs + (tl + 3) * 128 + (cb2 ^ SWZ(tl + 3))) = (ushort)(u23 >> 16);
        }
    }
    __syncthreads();                      // (3) zs visible cross-wave

    // ---- phase B (swapped): out^T[t][och] = z^T * Wout^T + bout ----
    const float bo_s = bout[wv * 16 + l15];
    f32x4 accO[4];
    #pragma unroll
    for (int tf = 0; tf < 4; ++tf) accO[tf] = (f32x4){bo_s, bo_s, bo_s, bo_s};

    short8 Bw = pW[4352 + (0 * 4 + wv) * 64 + lane];
    #pragma unroll
    for (int s2 = 0; s2 < 2; ++s2) {
        short8 Bwn = zero8;
        if (s2 == 0) Bwn = pW[4352 + (1 * 4 + wv) * 64 + lane];
        #pragma unroll
        for (int tf = 0; tf < 4; ++tf) {
            int colt = tf * 16 + l15;
            short8 Az = *(const short8*)(zs + colt * 128 + ((s2 * 64 + l4 * 16) ^ SWZ(colt)));
            accO[tf] = __builtin_amdgcn_mfma_f32_16x16x32_bf16(Az, Bw, accO[tf], 0, 0, 0);
        }
        Bw = Bwn;
    }

    // ---- coop skip store from zs (bf16 -> f32, 256B runs; intra-wave reads) ----
    #pragma unroll
    for (int i = 0; i < 4; ++i) {
        int c2 = wv * 16 + i * 4 + l4;     // this wave's own channels
        f32x4 v;
        #pragma unroll
        for (int r = 0; r < 4; ++r) {
            int row = l15 * 4 + r;
            ushort u = *(const ushort*)(zs + row * 128 + ((c2 * 2) ^ SWZ(row)));
            v[r] = __uint_as_float((uint)u << 16);
        }
        __builtin_nontemporal_store(v, (f32x4*)&skip[(size_t)(b * 64 + c2) * T_LEN + t0 + l15 * 4]);
    }
    __syncthreads();                      // (4) all zs reads done -> st overlay ok

    // ---- out staging + coop store: 256B-contiguous runs ----
    char* st = lds + XS_OFF;    // [64 ch][64 t] f32, 256B rows, slot ^= (ch&15)
    #pragma unroll
    for (int tf = 0; tf < 4; ++tf)
        *(f32x4*)(st + ch * 256 + (((tf * 4 + l4) ^ l15) << 4)) = accO[tf];
    #pragma unroll
    for (int i = 0; i < 4; ++i) {
        int c2 = wv * 16 + i * 4 + l4;
        f32x4 v = *(const f32x4*)(st + c2 * 256 + ((l15 ^ (i * 4 + l4)) << 4));
        __builtin_nontemporal_store(v, (f32x4*)&out[(size_t)(b * 64 + c2) * T_LEN + t0 + l15 * 4]);
    }
}

extern "C" void kernel_launch(void* const* d_in, const int* in_sizes, int n_in,
                              void* d_out, int out_size, void* d_ws, size_t ws_size,
                              hipStream_t stream) {
    const float* x     = (const float*)d_in[0];
    const float* cond  = (const float*)d_in[1];
    const float* wconv = (const float*)d_in[2];
    const float* bconv = (const float*)d_in[3];
    const float* wout  = (const float*)d_in[4];
    const float* bout  = (const float*)d_in[5];
    const float* wcond = (const float*)d_in[6];

    float* out  = (float*)d_out;
    float* skip = out + (size_t)8 * 64 * T_LEN;   // outputs concatenated in return order

    pack_weights<<<dim3(152), 256, 0, stream>>>(wconv, wcond, wout);
    wavenet_mfma<<<dim3(8 * (T_LEN / TT)), 256, 0, stream>>>(x, cond, bconv, bout, out, skip);
}